// Round 1
// baseline (1005.943 us; speedup 1.0000x reference)
//
#include <hip/hip_runtime.h>
#include <hip/hip_bf16.h>

typedef __bf16 bf16_t;
typedef __bf16 bf16x8 __attribute__((ext_vector_type(8)));
typedef float f32x4 __attribute__((ext_vector_type(4)));

#define LN_EPS 1e-6f

// ---------------- transpose + fp32->bf16 convert ----------------
// in: fp32 [R, C] row-major ; out: bf16 [C, R] row-major (out[c][r] = in[r][c])
__global__ void transpose_cvt_kernel(const float* __restrict__ in, bf16_t* __restrict__ out,
                                     int R, int C) {
    __shared__ float tile[32][33];
    int tx = threadIdx.x & 31;
    int ty = threadIdx.x >> 5;
    int r0 = blockIdx.y * 32;
    int c0 = blockIdx.x * 32;
#pragma unroll
    for (int i = 0; i < 4; i++) {
        int r = ty + i * 8;
        tile[r][tx] = in[(size_t)(r0 + r) * C + (c0 + tx)];
    }
    __syncthreads();
#pragma unroll
    for (int i = 0; i < 4; i++) {
        int r = ty + i * 8;
        out[(size_t)(c0 + r) * R + (r0 + tx)] = (bf16_t)tile[tx][r];
    }
}

// ---------------- LayerNorm (fp32 in) -> bf16 out ----------------
// one block of 256 threads per row, D = 1024 (each thread handles 4 floats)
__global__ void ln_kernel(const float* __restrict__ x, const float* __restrict__ g,
                          const float* __restrict__ bb, bf16_t* __restrict__ out, int D) {
    int row = blockIdx.x;
    int t = threadIdx.x;
    const float4* xr = reinterpret_cast<const float4*>(x + (size_t)row * D);
    float4 v = xr[t];
    float s = v.x + v.y + v.z + v.w;
    __shared__ float sbuf[4];
    __shared__ float sbuf2[4];
    int wave = t >> 6, lane = t & 63;
#pragma unroll
    for (int o = 32; o > 0; o >>= 1) s += __shfl_xor(s, o);
    if (lane == 0) sbuf[wave] = s;
    __syncthreads();
    float mean = (sbuf[0] + sbuf[1] + sbuf[2] + sbuf[3]) / (float)D;
    float d0 = v.x - mean, d1 = v.y - mean, d2 = v.z - mean, d3 = v.w - mean;
    float sq = d0 * d0 + d1 * d1 + d2 * d2 + d3 * d3;
#pragma unroll
    for (int o = 32; o > 0; o >>= 1) sq += __shfl_xor(sq, o);
    if (lane == 0) sbuf2[wave] = sq;
    __syncthreads();
    float var = (sbuf2[0] + sbuf2[1] + sbuf2[2] + sbuf2[3]) / (float)D;
    float inv = rsqrtf(var + LN_EPS);
    float4 gv = reinterpret_cast<const float4*>(g)[t];
    float4 bv = reinterpret_cast<const float4*>(bb)[t];
    bf16_t* o0 = out + (size_t)row * D + t * 4;
    o0[0] = (bf16_t)(d0 * inv * gv.x + bv.x);
    o0[1] = (bf16_t)(d1 * inv * gv.y + bv.y);
    o0[2] = (bf16_t)(d2 * inv * gv.z + bv.z);
    o0[3] = (bf16_t)(d3 * inv * gv.w + bv.w);
}

// ---------------- bf16 MFMA GEMM: C[M,N] = A[M,K] @ Bt[N,K]^T ----------------
// EPI 0: C fp32 = acc ; EPI 1: C fp32 = acc + aux ; EPI 2: Cb bf16 = silu(aux)*acc
#define BM 128
#define BN 128
#define BKK 32

template <int EPI>
__launch_bounds__(256, 2) __global__
void gemm_kernel(const bf16_t* __restrict__ A, const bf16_t* __restrict__ Bt,
                 float* __restrict__ Cf, const float* __restrict__ aux,
                 bf16_t* __restrict__ Cb, int M, int N, int K) {
    __shared__ __align__(16) bf16_t As[BM * BKK];
    __shared__ __align__(16) bf16_t Bs[BN * BKK];
    int t = threadIdx.x;
    int m0 = blockIdx.y * BM;
    int n0 = blockIdx.x * BN;
    int wave = t >> 6, lane = t & 63;
    int wm = (wave >> 1) * 64, wn = (wave & 1) * 64;
    int lr = lane & 15;    // row (A) / col (B,C) within 16x16 tile
    int quad = lane >> 4;  // 0..3

    f32x4 acc[4][4];
#pragma unroll
    for (int mi = 0; mi < 4; mi++)
#pragma unroll
        for (int ni = 0; ni < 4; ni++) acc[mi][ni] = 0.f;

    for (int k0 = 0; k0 < K; k0 += BKK) {
        // stage A/B tiles: 512 16-byte chunks each, 256 threads x 2
#pragma unroll
        for (int i = 0; i < 2; i++) {
            int c = t + i * 256;
            int row = c >> 2;
            int col8 = (c & 3) * 8;
            reinterpret_cast<int4*>(As)[c] =
                *reinterpret_cast<const int4*>(A + (size_t)(m0 + row) * K + k0 + col8);
            reinterpret_cast<int4*>(Bs)[c] =
                *reinterpret_cast<const int4*>(Bt + (size_t)(n0 + row) * K + k0 + col8);
        }
        __syncthreads();
        bf16x8 af[4], bfv[4];
#pragma unroll
        for (int mi = 0; mi < 4; mi++)
            af[mi] = *reinterpret_cast<const bf16x8*>(&As[(wm + mi * 16 + lr) * BKK + quad * 8]);
#pragma unroll
        for (int ni = 0; ni < 4; ni++)
            bfv[ni] = *reinterpret_cast<const bf16x8*>(&Bs[(wn + ni * 16 + lr) * BKK + quad * 8]);
#pragma unroll
        for (int mi = 0; mi < 4; mi++)
#pragma unroll
            for (int ni = 0; ni < 4; ni++)
                acc[mi][ni] = __builtin_amdgcn_mfma_f32_16x16x32_bf16(af[mi], bfv[ni],
                                                                      acc[mi][ni], 0, 0, 0);
        __syncthreads();
    }
#pragma unroll
    for (int mi = 0; mi < 4; mi++) {
#pragma unroll
        for (int ni = 0; ni < 4; ni++) {
#pragma unroll
            for (int j = 0; j < 4; j++) {
                int gm = m0 + wm + mi * 16 + quad * 4 + j;
                int gn = n0 + wn + ni * 16 + lr;
                size_t idx = (size_t)gm * N + gn;
                float val = acc[mi][ni][j];
                if constexpr (EPI == 0) {
                    Cf[idx] = val;
                } else if constexpr (EPI == 1) {
                    Cf[idx] = val + aux[idx];
                } else {
                    float a = aux[idx];
                    float sl = a / (1.0f + expf(-a));
                    Cb[idx] = (bf16_t)(sl * val);
                }
            }
        }
    }
}

// ---------------- RoPE (in-place on q and k, fp32) ----------------
// grid.x = B*S, block = 512 (h = t>>5 in 0..15, i = t&31 in 0..31), hd=64
__global__ void rope_kernel(float* __restrict__ q, float* __restrict__ k, int S) {
    int bs = blockIdx.x;
    int s = bs & (S - 1);
    int t = threadIdx.x;
    int h = t >> 5, i = t & 31;
    float freq = powf(10000.0f, -(float)(2 * i) / 64.0f);
    float ang = (float)s * freq;
    float sn, cs;
    sincosf(ang, &sn, &cs);
    size_t base = (size_t)bs * 1024 + h * 64 + i;
    float x1 = q[base], x2 = q[base + 32];
    q[base] = x1 * cs - x2 * sn;
    q[base + 32] = x2 * cs + x1 * sn;
    x1 = k[base]; x2 = k[base + 32];
    k[base] = x1 * cs - x2 * sn;
    k[base + 32] = x2 * cs + x1 * sn;
}

// ---------------- sliding-window causal attention ----------------
// grid (S/16, H, B), 256 threads. 16 queries/block, window keys staged in LDS (bf16).
#define QB 16
#define KMAX 272
#define KPAD 68
__global__ __launch_bounds__(256) void attn_kernel(const float* __restrict__ q,
                                                   const float* __restrict__ k,
                                                   const float* __restrict__ v,
                                                   bf16_t* __restrict__ ctx, int S) {
    __shared__ bf16_t Ks[KMAX][KPAD];
    __shared__ bf16_t Vs[KMAX][KPAD];
    __shared__ float Qs[QB][64];
    __shared__ float Sc[QB][KMAX];
    __shared__ float inv_s[QB];

    int qb = blockIdx.x, h = blockIdx.y, b = blockIdx.z;
    int q0 = qb * QB;
    int jmin = q0 - 255; if (jmin < 0) jmin = 0;
    int jmax = q0 + QB - 1;
    int cnt = jmax - jmin + 1;  // <= 271
    int t = threadIdx.x;

    const float* qbase = q + (size_t)(b * S + q0) * 1024 + h * 64;
    for (int idx = t; idx < QB * 64; idx += 256) {
        int qi = idx >> 6, d = idx & 63;
        Qs[qi][d] = qbase[(size_t)qi * 1024 + d];
    }
    const float* kb = k + (size_t)(b * S + jmin) * 1024 + h * 64;
    const float* vb = v + (size_t)(b * S + jmin) * 1024 + h * 64;
    for (int idx = t; idx < cnt * 64; idx += 256) {
        int jj = idx >> 6, d = idx & 63;
        Ks[jj][d] = (bf16_t)kb[(size_t)jj * 1024 + d];
        Vs[jj][d] = (bf16_t)vb[(size_t)jj * 1024 + d];
    }
    __syncthreads();

    // scores: QB*KMAX = 4352 = 17 * 256
    for (int p = t; p < QB * KMAX; p += 256) {
        int qi = p / KMAX, jj = p % KMAX;
        int iabs = q0 + qi;
        int j = jmin + jj;
        float sc = -1e9f;
        if (jj < cnt && j <= iabs && (iabs - j) < 256) {
            float dot = 0.f;
#pragma unroll
            for (int d = 0; d < 64; d++) dot += Qs[qi][d] * (float)Ks[jj][d];
            sc = dot * 0.125f;
        }
        Sc[qi][jj] = sc;
    }
    __syncthreads();

    int wave = t >> 6, lane = t & 63;
    for (int qi = wave; qi < QB; qi += 4) {
        float m = -1e9f;
        for (int jj = lane; jj < KMAX; jj += 64) m = fmaxf(m, Sc[qi][jj]);
#pragma unroll
        for (int o = 32; o > 0; o >>= 1) m = fmaxf(m, __shfl_xor(m, o));
        float sum = 0.f;
        for (int jj = lane; jj < KMAX; jj += 64) {
            float p = __expf(Sc[qi][jj] - m);
            Sc[qi][jj] = p;
            sum += p;
        }
#pragma unroll
        for (int o = 32; o > 0; o >>= 1) sum += __shfl_xor(sum, o);
        if (lane == 0) inv_s[qi] = 1.0f / sum;
    }
    __syncthreads();

    int d = t & 63, qg = t >> 6;
    for (int qi = qg; qi < QB; qi += 4) {
        float a = 0.f;
        for (int jj = 0; jj < cnt; jj++) a += Sc[qi][jj] * (float)Vs[jj][d];
        int iabs = q0 + qi;
        ctx[(size_t)(b * S + iabs) * 1024 + h * 64 + d] = (bf16_t)(a * inv_s[qi]);
    }
}

// ---------------- launch ----------------
extern "C" void kernel_launch(void* const* d_in, const int* in_sizes, int n_in,
                              void* d_out, int out_size, void* d_ws, size_t ws_size,
                              hipStream_t stream) {
    const float* hs   = (const float*)d_in[0];
    const float* wq   = (const float*)d_in[1];
    const float* wk   = (const float*)d_in[2];
    const float* wv   = (const float*)d_in[3];
    const float* wo   = (const float*)d_in[4];
    const float* w1   = (const float*)d_in[5];
    const float* w2   = (const float*)d_in[6];
    const float* w3   = (const float*)d_in[7];
    const float* ln1g = (const float*)d_in[8];
    const float* ln1b = (const float*)d_in[9];
    const float* ln2g = (const float*)d_in[10];
    const float* ln2b = (const float*)d_in[11];
    float* out = (float*)d_out;

    const int B = 2, S = 2048, D = 1024, I = 4096;
    const int BS = B * S;  // 4096 rows

    char* ws = (char*)d_ws;
    const size_t MB = 1024 * 1024;
    bf16_t* wq_t = (bf16_t*)(ws + 0 * MB);    // 2MB
    bf16_t* wk_t = (bf16_t*)(ws + 2 * MB);    // 2MB
    bf16_t* wv_t = (bf16_t*)(ws + 4 * MB);    // 2MB
    bf16_t* wo_t = (bf16_t*)(ws + 6 * MB);    // 2MB
    bf16_t* w1_t = (bf16_t*)(ws + 8 * MB);    // 8MB  [I,D]
    bf16_t* w3_t = (bf16_t*)(ws + 16 * MB);   // 8MB  [I,D]
    bf16_t* w2_t = (bf16_t*)(ws + 24 * MB);   // 8MB  [D,I]
    bf16_t* x_b  = (bf16_t*)(ws + 32 * MB);   // 8MB
    float*  qf   = (float*)(ws + 40 * MB);    // 16MB
    float*  kf   = (float*)(ws + 56 * MB);    // 16MB
    float*  vf   = (float*)(ws + 72 * MB);    // 16MB
    bf16_t* ctxb = (bf16_t*)(ws + 88 * MB);   // 8MB
    bf16_t* x2_b = (bf16_t*)(ws + 96 * MB);   // 8MB
    float*  hid  = (float*)(ws + 104 * MB);   // 16MB
    bf16_t* hbuf = (bf16_t*)(ws + 120 * MB);  // 32MB -> total 152MB
    float*  h1   = (float*)(ws + 32 * MB);    // 64MB, aliases x_b/q/k/v/ctxb (dead then)

    dim3 tb(256);
    // weights -> bf16, transposed to [N,K]
    transpose_cvt_kernel<<<dim3(D / 32, D / 32), tb, 0, stream>>>(wq, wq_t, D, D);
    transpose_cvt_kernel<<<dim3(D / 32, D / 32), tb, 0, stream>>>(wk, wk_t, D, D);
    transpose_cvt_kernel<<<dim3(D / 32, D / 32), tb, 0, stream>>>(wv, wv_t, D, D);
    transpose_cvt_kernel<<<dim3(D / 32, D / 32), tb, 0, stream>>>(wo, wo_t, D, D);
    transpose_cvt_kernel<<<dim3(I / 32, D / 32), tb, 0, stream>>>(w1, w1_t, D, I);
    transpose_cvt_kernel<<<dim3(I / 32, D / 32), tb, 0, stream>>>(w3, w3_t, D, I);
    transpose_cvt_kernel<<<dim3(D / 32, I / 32), tb, 0, stream>>>(w2, w2_t, I, D);

    ln_kernel<<<BS, tb, 0, stream>>>(hs, ln1g, ln1b, x_b, D);

    gemm_kernel<0><<<dim3(D / BN, BS / BM), tb, 0, stream>>>(x_b, wq_t, qf, nullptr, nullptr, BS, D, D);
    gemm_kernel<0><<<dim3(D / BN, BS / BM), tb, 0, stream>>>(x_b, wk_t, kf, nullptr, nullptr, BS, D, D);
    gemm_kernel<0><<<dim3(D / BN, BS / BM), tb, 0, stream>>>(x_b, wv_t, vf, nullptr, nullptr, BS, D, D);

    rope_kernel<<<BS, dim3(512), 0, stream>>>(qf, kf, S);

    attn_kernel<<<dim3(S / QB, 16, B), tb, 0, stream>>>(qf, kf, vf, ctxb, S);

    gemm_kernel<1><<<dim3(D / BN, BS / BM), tb, 0, stream>>>(ctxb, wo_t, hid, hs, nullptr, BS, D, D);

    ln_kernel<<<BS, tb, 0, stream>>>(hid, ln2g, ln2b, x2_b, D);

    gemm_kernel<0><<<dim3(I / BN, BS / BM), tb, 0, stream>>>(x2_b, w1_t, h1, nullptr, nullptr, BS, I, D);
    gemm_kernel<2><<<dim3(I / BN, BS / BM), tb, 0, stream>>>(x2_b, w3_t, nullptr, h1, hbuf, BS, I, D);
    gemm_kernel<1><<<dim3(D / BN, BS / BM), tb, 0, stream>>>(hbuf, w2_t, out, hid, nullptr, BS, D, I);
}

// Round 2
// 474.780 us; speedup vs baseline: 2.1188x; 2.1188x over previous
//
#include <hip/hip_runtime.h>
#include <hip/hip_bf16.h>

typedef __bf16 bf16_t;
typedef __bf16 bf16x8 __attribute__((ext_vector_type(8)));
typedef float f32x4 __attribute__((ext_vector_type(4)));

#define LN_EPS 1e-6f

// ---------------- transpose + fp32->bf16 convert (weights) ----------------
__global__ void transpose_cvt_kernel(const float* __restrict__ in, bf16_t* __restrict__ out,
                                     int R, int C) {
    __shared__ float tile[32][33];
    int tx = threadIdx.x & 31;
    int ty = threadIdx.x >> 5;
    int r0 = blockIdx.y * 32;
    int c0 = blockIdx.x * 32;
#pragma unroll
    for (int i = 0; i < 4; i++) {
        int r = ty + i * 8;
        tile[r][tx] = in[(size_t)(r0 + r) * C + (c0 + tx)];
    }
    __syncthreads();
#pragma unroll
    for (int i = 0; i < 4; i++) {
        int r = ty + i * 8;
        out[(size_t)(c0 + r) * R + (r0 + tx)] = (bf16_t)tile[tx][r];
    }
}

// ---------------- LayerNorm (fp32 in) -> bf16 out ----------------
__global__ void ln_kernel(const float* __restrict__ x, const float* __restrict__ g,
                          const float* __restrict__ bb, bf16_t* __restrict__ out, int D) {
    int row = blockIdx.x;
    int t = threadIdx.x;
    const float4* xr = reinterpret_cast<const float4*>(x + (size_t)row * D);
    float4 v = xr[t];
    float s = v.x + v.y + v.z + v.w;
    __shared__ float sbuf[4];
    __shared__ float sbuf2[4];
    int wave = t >> 6, lane = t & 63;
#pragma unroll
    for (int o = 32; o > 0; o >>= 1) s += __shfl_xor(s, o);
    if (lane == 0) sbuf[wave] = s;
    __syncthreads();
    float mean = (sbuf[0] + sbuf[1] + sbuf[2] + sbuf[3]) / (float)D;
    float d0 = v.x - mean, d1 = v.y - mean, d2 = v.z - mean, d3 = v.w - mean;
    float sq = d0 * d0 + d1 * d1 + d2 * d2 + d3 * d3;
#pragma unroll
    for (int o = 32; o > 0; o >>= 1) sq += __shfl_xor(sq, o);
    if (lane == 0) sbuf2[wave] = sq;
    __syncthreads();
    float var = (sbuf2[0] + sbuf2[1] + sbuf2[2] + sbuf2[3]) / (float)D;
    float inv = rsqrtf(var + LN_EPS);
    float4 gv = reinterpret_cast<const float4*>(g)[t];
    float4 bv = reinterpret_cast<const float4*>(bb)[t];
    bf16_t* o0 = out + (size_t)row * D + t * 4;
    o0[0] = (bf16_t)(d0 * inv * gv.x + bv.x);
    o0[1] = (bf16_t)(d1 * inv * gv.y + bv.y);
    o0[2] = (bf16_t)(d2 * inv * gv.z + bv.z);
    o0[3] = (bf16_t)(d3 * inv * gv.w + bv.w);
}

// ---------------- bf16 MFMA GEMM: C[M,N] = A[M,K] @ Bt[N,K]^T ----------------
// EPI 0: Cf = acc
// EPI 1: Cf = acc + aux (fp32)
// EPI 2: Cb = silu(auxb) * acc   (bf16 out, bf16 aux)
// EPI 3: Cb = RoPE(acc) (bf16 out; rows are tokens, cols are H*hd features)
// EPI 4: Cb = acc (bf16 out)
#define BM 128
#define BN 128
#define BKK 32

template <int EPI>
__launch_bounds__(256, 2) __global__
void gemm_kernel(const bf16_t* __restrict__ A, const bf16_t* __restrict__ Bt,
                 float* __restrict__ Cf, const float* __restrict__ aux,
                 const bf16_t* __restrict__ auxb, bf16_t* __restrict__ Cb,
                 int M, int N, int K) {
    __shared__ __align__(16) bf16_t As[BM * BKK];
    __shared__ __align__(16) bf16_t Bs[BN * BKK];
    int t = threadIdx.x;
    int m0 = blockIdx.y * BM;
    int n0 = blockIdx.x * BN;
    int wave = t >> 6, lane = t & 63;
    int wm = (wave >> 1) * 64, wn = (wave & 1) * 64;
    int lr = lane & 15;
    int quad = lane >> 4;

    f32x4 acc[4][4];
#pragma unroll
    for (int mi = 0; mi < 4; mi++)
#pragma unroll
        for (int ni = 0; ni < 4; ni++) acc[mi][ni] = 0.f;

    for (int k0 = 0; k0 < K; k0 += BKK) {
#pragma unroll
        for (int i = 0; i < 2; i++) {
            int c = t + i * 256;
            int row = c >> 2;
            int col8 = (c & 3) * 8;
            reinterpret_cast<int4*>(As)[c] =
                *reinterpret_cast<const int4*>(A + (size_t)(m0 + row) * K + k0 + col8);
            reinterpret_cast<int4*>(Bs)[c] =
                *reinterpret_cast<const int4*>(Bt + (size_t)(n0 + row) * K + k0 + col8);
        }
        __syncthreads();
        bf16x8 af[4], bfv[4];
#pragma unroll
        for (int mi = 0; mi < 4; mi++)
            af[mi] = *reinterpret_cast<const bf16x8*>(&As[(wm + mi * 16 + lr) * BKK + quad * 8]);
#pragma unroll
        for (int ni = 0; ni < 4; ni++)
            bfv[ni] = *reinterpret_cast<const bf16x8*>(&Bs[(wn + ni * 16 + lr) * BKK + quad * 8]);
#pragma unroll
        for (int mi = 0; mi < 4; mi++)
#pragma unroll
            for (int ni = 0; ni < 4; ni++)
                acc[mi][ni] = __builtin_amdgcn_mfma_f32_16x16x32_bf16(af[mi], bfv[ni],
                                                                      acc[mi][ni], 0, 0, 0);
        __syncthreads();
    }
    if constexpr (EPI == 3) {
        // fused RoPE: feature i pairs with i+32 within a head; ni in {0,1} pairs ni+2
        const float kfreq = -0.41524101186f;  // -log2(10000)/32
#pragma unroll
        for (int mi = 0; mi < 4; mi++) {
#pragma unroll
            for (int j = 0; j < 4; j++) {
                int gm = m0 + wm + mi * 16 + quad * 4 + j;
                float sf = (float)(gm & 2047);  // position within sequence (S=2048)
#pragma unroll
                for (int ni = 0; ni < 2; ni++) {
                    int ip = ni * 16 + lr;  // i' in 0..31
                    float freq = exp2f((float)ip * kfreq);
                    float ang = sf * freq;
                    float sn, cs;
                    __sincosf(ang, &sn, &cs);
                    float x1 = acc[mi][ni][j], x2 = acc[mi][ni + 2][j];
                    size_t idx = (size_t)gm * N + n0 + wn + ni * 16 + lr;
                    Cb[idx] = (bf16_t)(x1 * cs - x2 * sn);
                    Cb[idx + 32] = (bf16_t)(x2 * cs + x1 * sn);
                }
            }
        }
    } else {
#pragma unroll
        for (int mi = 0; mi < 4; mi++) {
#pragma unroll
            for (int ni = 0; ni < 4; ni++) {
#pragma unroll
                for (int j = 0; j < 4; j++) {
                    int gm = m0 + wm + mi * 16 + quad * 4 + j;
                    int gn = n0 + wn + ni * 16 + lr;
                    size_t idx = (size_t)gm * N + gn;
                    float val = acc[mi][ni][j];
                    if constexpr (EPI == 0) {
                        Cf[idx] = val;
                    } else if constexpr (EPI == 1) {
                        Cf[idx] = val + aux[idx];
                    } else if constexpr (EPI == 2) {
                        float a = (float)auxb[idx];
                        float sl = a / (1.0f + __expf(-a));
                        Cb[idx] = (bf16_t)(sl * val);
                    } else {  // EPI 4
                        Cb[idx] = (bf16_t)val;
                    }
                }
            }
        }
    }
}

// ---------------- V transpose: vb [B*S, H*64] -> vt [B, H, 64, S] ----------------
__global__ void transpose_v_kernel(const bf16_t* __restrict__ v, bf16_t* __restrict__ vt, int S) {
    __shared__ bf16_t tile[64][66];
    int t = threadIdx.x;
    int s0 = blockIdx.x * 64;
    int h = blockIdx.y, b = blockIdx.z;
#pragma unroll
    for (int i = 0; i < 2; i++) {
        int c = t + i * 256;
        int ss = c >> 3, d8 = (c & 7) * 8;
        bf16x8 val = *reinterpret_cast<const bf16x8*>(
            &v[((size_t)(b * S + s0 + ss) * 16 + h) * 64 + d8]);
#pragma unroll
        for (int jj = 0; jj < 8; jj++) tile[ss][d8 + jj] = val[jj];
    }
    __syncthreads();
#pragma unroll
    for (int i = 0; i < 2; i++) {
        int c = t + i * 256;
        int d = c >> 3, s8 = (c & 7) * 8;
        bf16x8 o;
#pragma unroll
        for (int jj = 0; jj < 8; jj++) o[jj] = tile[s8 + jj][d];
        *reinterpret_cast<bf16x8*>(&vt[(((size_t)(b * 16 + h)) * 64 + d) * S + s0 + s8]) = o;
    }
}

// ---------------- MFMA sliding-window attention ----------------
// grid (S/64, H, B), 256 threads = 4 waves; each wave owns a 16-query tile.
// q,k: bf16 [B*S, H*64] (RoPE applied). vt: bf16 [B,H,64,S]. ctx out bf16 [B*S, H*64].
#define PSTR 40
__global__ __launch_bounds__(256, 2) void attn_kernel(const bf16_t* __restrict__ q,
                                                      const bf16_t* __restrict__ k,
                                                      const bf16_t* __restrict__ vt,
                                                      bf16_t* __restrict__ ctx, int S) {
    __shared__ __align__(16) bf16_t Pbuf[4][16 * PSTR];
    int t = threadIdx.x;
    int wave = t >> 6, lane = t & 63;
    int col = lane & 15, quad = lane >> 4;
    int h = blockIdx.y, b = blockIdx.z;
    int q0 = blockIdx.x * 64 + wave * 16;

    // Q A-frags: lane holds Q[q0+col][quad*8+j (+32)]
    const bf16_t* qrow = q + ((size_t)(b * S + q0 + col) * 16 + h) * 64;
    bf16x8 aq0 = *reinterpret_cast<const bf16x8*>(qrow + quad * 8);
    bf16x8 aq1 = *reinterpret_cast<const bf16x8*>(qrow + 32 + quad * 8);

    int jbase = q0 - 256;
    f32x4 sc[18];
    // QK^T: 18 key tiles of 16 (covers [q0-256, q0+31]); B-frag lane = key col
#pragma unroll
    for (int kt = 0; kt < 18; kt++) {
        int j = jbase + kt * 16 + col;
        int jc = j < 0 ? 0 : (j > S - 1 ? S - 1 : j);
        const bf16_t* krow = k + ((size_t)(b * S + jc) * 16 + h) * 64;
        bf16x8 bk0 = *reinterpret_cast<const bf16x8*>(krow + quad * 8);
        bf16x8 bk1 = *reinterpret_cast<const bf16x8*>(krow + 32 + quad * 8);
        f32x4 c0 = {0.f, 0.f, 0.f, 0.f};
        c0 = __builtin_amdgcn_mfma_f32_16x16x32_bf16(aq0, bk0, c0, 0, 0, 0);
        c0 = __builtin_amdgcn_mfma_f32_16x16x32_bf16(aq1, bk1, c0, 0, 0, 0);
        sc[kt] = c0;
    }
    // mask + scale (C layout: row = quad*4+jj, col = lane&15)
#pragma unroll
    for (int kt = 0; kt < 18; kt++) {
#pragma unroll
        for (int jj = 0; jj < 4; jj++) {
            int qq = quad * 4 + jj;
            int j = jbase + kt * 16 + col;
            int rel = (q0 + qq) - j;
            bool ok = (j >= 0) && (rel >= 0) && (rel < 256);
            sc[kt][jj] = ok ? sc[kt][jj] * 0.125f : -1e30f;
        }
    }
    // exact softmax per query row (reduce across 16 col-lanes within the quad)
    float sminv[4];
#pragma unroll
    for (int jj = 0; jj < 4; jj++) {
        float m = -1e30f;
#pragma unroll
        for (int kt = 0; kt < 18; kt++) m = fmaxf(m, sc[kt][jj]);
#pragma unroll
        for (int o = 1; o < 16; o <<= 1) m = fmaxf(m, __shfl_xor(m, o));
        float s = 0.f;
#pragma unroll
        for (int kt = 0; kt < 18; kt++) {
            float p = __expf(sc[kt][jj] - m);
            sc[kt][jj] = p;
            s += p;
        }
#pragma unroll
        for (int o = 1; o < 16; o <<= 1) s += __shfl_xor(s, o);
        sminv[jj] = 1.0f / s;
    }
    // PV: 9 chunks of 32 keys; P round-trips through per-wave LDS
    f32x4 o[4];
#pragma unroll
    for (int n = 0; n < 4; n++) o[n] = 0.f;
    bf16_t* myP = Pbuf[wave];
    const bf16_t* vplane = vt + ((size_t)(b * 16 + h)) * 64 * S;
#pragma unroll
    for (int c = 0; c < 9; c++) {
#pragma unroll
        for (int half = 0; half < 2; half++) {
            int kt = 2 * c + half;
#pragma unroll
            for (int jj = 0; jj < 4; jj++) {
                int qq = quad * 4 + jj;
                myP[qq * PSTR + half * 16 + col] = (bf16_t)(sc[kt][jj] * sminv[jj]);
            }
        }
        bf16x8 ap = *reinterpret_cast<const bf16x8*>(myP + col * PSTR + quad * 8);
        int key0 = jbase + c * 32 + quad * 8;
        int kc = key0 < 0 ? 0 : (key0 > S - 8 ? S - 8 : key0);
#pragma unroll
        for (int n = 0; n < 4; n++) {
            bf16x8 bv = *reinterpret_cast<const bf16x8*>(vplane + ((size_t)(n * 16 + col)) * S + kc);
            o[n] = __builtin_amdgcn_mfma_f32_16x16x32_bf16(ap, bv, o[n], 0, 0, 0);
        }
    }
    // epilogue: C layout row = query (quad*4+jj), col = d within n-tile
#pragma unroll
    for (int n = 0; n < 4; n++)
#pragma unroll
        for (int jj = 0; jj < 4; jj++) {
            int qq = quad * 4 + jj;
            ctx[((size_t)(b * S + q0 + qq) * 16 + h) * 64 + n * 16 + col] = (bf16_t)o[n][jj];
        }
}

// ---------------- launch ----------------
extern "C" void kernel_launch(void* const* d_in, const int* in_sizes, int n_in,
                              void* d_out, int out_size, void* d_ws, size_t ws_size,
                              hipStream_t stream) {
    const float* hs   = (const float*)d_in[0];
    const float* wq   = (const float*)d_in[1];
    const float* wk   = (const float*)d_in[2];
    const float* wv   = (const float*)d_in[3];
    const float* wo   = (const float*)d_in[4];
    const float* w1   = (const float*)d_in[5];
    const float* w2   = (const float*)d_in[6];
    const float* w3   = (const float*)d_in[7];
    const float* ln1g = (const float*)d_in[8];
    const float* ln1b = (const float*)d_in[9];
    const float* ln2g = (const float*)d_in[10];
    const float* ln2b = (const float*)d_in[11];
    float* out = (float*)d_out;

    const int B = 2, S = 2048, D = 1024, I = 4096;
    const int BS = B * S;

    char* ws = (char*)d_ws;
    const size_t MB = 1024 * 1024;
    bf16_t* wq_t = (bf16_t*)(ws + 0 * MB);
    bf16_t* wk_t = (bf16_t*)(ws + 2 * MB);
    bf16_t* wv_t = (bf16_t*)(ws + 4 * MB);
    bf16_t* wo_t = (bf16_t*)(ws + 6 * MB);
    bf16_t* w1_t = (bf16_t*)(ws + 8 * MB);
    bf16_t* w3_t = (bf16_t*)(ws + 16 * MB);
    bf16_t* w2_t = (bf16_t*)(ws + 24 * MB);
    bf16_t* x_b  = (bf16_t*)(ws + 32 * MB);
    float*  hid  = (float*)(ws + 40 * MB);   // 16 MB
    bf16_t* x2_b = (bf16_t*)(ws + 56 * MB);  // 8 MB
    bf16_t* qb   = (bf16_t*)(ws + 64 * MB);  // 8 MB
    bf16_t* kb   = (bf16_t*)(ws + 72 * MB);  // 8 MB
    bf16_t* vb   = (bf16_t*)(ws + 80 * MB);  // 8 MB
    bf16_t* vt   = (bf16_t*)(ws + 88 * MB);  // 8 MB
    bf16_t* ctxb = (bf16_t*)(ws + 96 * MB);  // 8 MB
    bf16_t* h1b  = (bf16_t*)(ws + 64 * MB);  // 32 MB, aliases qb/kb/vb/vt (dead post-attn)
    bf16_t* hbuf = (bf16_t*)(ws + 96 * MB);  // 32 MB, aliases ctxb (dead post-Wo); end 128 MB

    dim3 tb(256);
    transpose_cvt_kernel<<<dim3(D / 32, D / 32), tb, 0, stream>>>(wq, wq_t, D, D);
    transpose_cvt_kernel<<<dim3(D / 32, D / 32), tb, 0, stream>>>(wk, wk_t, D, D);
    transpose_cvt_kernel<<<dim3(D / 32, D / 32), tb, 0, stream>>>(wv, wv_t, D, D);
    transpose_cvt_kernel<<<dim3(D / 32, D / 32), tb, 0, stream>>>(wo, wo_t, D, D);
    transpose_cvt_kernel<<<dim3(I / 32, D / 32), tb, 0, stream>>>(w1, w1_t, D, I);
    transpose_cvt_kernel<<<dim3(I / 32, D / 32), tb, 0, stream>>>(w3, w3_t, D, I);
    transpose_cvt_kernel<<<dim3(D / 32, I / 32), tb, 0, stream>>>(w2, w2_t, I, D);

    ln_kernel<<<BS, tb, 0, stream>>>(hs, ln1g, ln1b, x_b, D);

    gemm_kernel<3><<<dim3(D / BN, BS / BM), tb, 0, stream>>>(x_b, wq_t, nullptr, nullptr, nullptr, qb, BS, D, D);
    gemm_kernel<3><<<dim3(D / BN, BS / BM), tb, 0, stream>>>(x_b, wk_t, nullptr, nullptr, nullptr, kb, BS, D, D);
    gemm_kernel<4><<<dim3(D / BN, BS / BM), tb, 0, stream>>>(x_b, wv_t, nullptr, nullptr, nullptr, vb, BS, D, D);

    transpose_v_kernel<<<dim3(S / 64, 16, B), tb, 0, stream>>>(vb, vt, S);

    attn_kernel<<<dim3(S / 64, 16, B), tb, 0, stream>>>(qb, kb, vt, ctxb, S);

    gemm_kernel<1><<<dim3(D / BN, BS / BM), tb, 0, stream>>>(ctxb, wo_t, hid, hs, nullptr, nullptr, BS, D, D);

    ln_kernel<<<BS, tb, 0, stream>>>(hid, ln2g, ln2b, x2_b, D);

    gemm_kernel<4><<<dim3(I / BN, BS / BM), tb, 0, stream>>>(x2_b, w1_t, nullptr, nullptr, nullptr, h1b, BS, I, D);
    gemm_kernel<2><<<dim3(I / BN, BS / BM), tb, 0, stream>>>(x2_b, w3_t, nullptr, nullptr, h1b, hbuf, BS, I, D);
    gemm_kernel<1><<<dim3(D / BN, BS / BM), tb, 0, stream>>>(hbuf, w2_t, out, hid, nullptr, nullptr, BS, D, I);
}

// Round 4
// 429.462 us; speedup vs baseline: 2.3423x; 1.1055x over previous
//
#include <hip/hip_runtime.h>
#include <hip/hip_bf16.h>

typedef __bf16 bf16_t;
typedef __bf16 bf16x8 __attribute__((ext_vector_type(8)));
typedef float f32x4 __attribute__((ext_vector_type(4)));

#define LN_EPS 1e-6f

__device__ __forceinline__ void gl2lds16(const void* g, void* l) {
    __builtin_amdgcn_global_load_lds(
        (const __attribute__((address_space(1))) void*)g,
        (__attribute__((address_space(3))) void*)l, 16, 0, 0);
}

// ---------------- transpose + fp32->bf16 convert (weights) ----------------
__global__ void transpose_cvt_kernel(const float* __restrict__ in, bf16_t* __restrict__ out,
                                     int R, int C) {
    __shared__ float tile[32][33];
    int tx = threadIdx.x & 31;
    int ty = threadIdx.x >> 5;
    int r0 = blockIdx.y * 32;
    int c0 = blockIdx.x * 32;
#pragma unroll
    for (int i = 0; i < 4; i++) {
        int r = ty + i * 8;
        tile[r][tx] = in[(size_t)(r0 + r) * C + (c0 + tx)];
    }
    __syncthreads();
#pragma unroll
    for (int i = 0; i < 4; i++) {
        int r = ty + i * 8;
        out[(size_t)(c0 + r) * R + (r0 + tx)] = (bf16_t)tile[tx][r];
    }
}

// ---------------- LayerNorm (fp32 in) -> bf16 out ----------------
__global__ void ln_kernel(const float* __restrict__ x, const float* __restrict__ g,
                          const float* __restrict__ bb, bf16_t* __restrict__ out, int D) {
    int row = blockIdx.x;
    int t = threadIdx.x;
    const float4* xr = reinterpret_cast<const float4*>(x + (size_t)row * D);
    float4 v = xr[t];
    float s = v.x + v.y + v.z + v.w;
    __shared__ float sbuf[4];
    __shared__ float sbuf2[4];
    int wave = t >> 6, lane = t & 63;
#pragma unroll
    for (int o = 32; o > 0; o >>= 1) s += __shfl_xor(s, o);
    if (lane == 0) sbuf[wave] = s;
    __syncthreads();
    float mean = (sbuf[0] + sbuf[1] + sbuf[2] + sbuf[3]) / (float)D;
    float d0 = v.x - mean, d1 = v.y - mean, d2 = v.z - mean, d3 = v.w - mean;
    float sq = d0 * d0 + d1 * d1 + d2 * d2 + d3 * d3;
#pragma unroll
    for (int o = 32; o > 0; o >>= 1) sq += __shfl_xor(sq, o);
    if (lane == 0) sbuf2[wave] = sq;
    __syncthreads();
    float var = (sbuf2[0] + sbuf2[1] + sbuf2[2] + sbuf2[3]) / (float)D;
    float inv = rsqrtf(var + LN_EPS);
    float4 gv = reinterpret_cast<const float4*>(g)[t];
    float4 bv = reinterpret_cast<const float4*>(bb)[t];
    bf16_t* o0 = out + (size_t)row * D + t * 4;
    o0[0] = (bf16_t)(d0 * inv * gv.x + bv.x);
    o0[1] = (bf16_t)(d1 * inv * gv.y + bv.y);
    o0[2] = (bf16_t)(d2 * inv * gv.z + bv.z);
    o0[3] = (bf16_t)(d3 * inv * gv.w + bv.w);
}

// ---------------- bf16 MFMA GEMM: C[M,N] = A[M,K] @ Bt[N,K]^T ----------------
// EPI 0: Cf = acc
// EPI 1: Cf = acc + aux (fp32)
// EPI 2: Cb = silu(auxb) * acc   (bf16 out, bf16 aux)
// EPI 3: fused QKV: cols <2048 -> RoPE(acc) bf16 ; cols >=2048 -> plain bf16
// EPI 4: Cb = acc (bf16 out)
#define BM 128
#define BN 128
#define BKK 32

template <int EPI>
__launch_bounds__(256, 2) __global__
void gemm_kernel(const bf16_t* __restrict__ A, const bf16_t* __restrict__ Bt,
                 float* __restrict__ Cf, const float* __restrict__ aux,
                 const bf16_t* __restrict__ auxb, bf16_t* __restrict__ Cb,
                 int M, int N, int K) {
    __shared__ __align__(16) bf16_t As[BM * BKK];
    __shared__ __align__(16) bf16_t Bs[BN * BKK];
    int t = threadIdx.x;
    // swizzled tile mapping: groups of 8 N-tiles spanning all M-tiles (L2 reuse)
    int lin = blockIdx.y * gridDim.x + blockIdx.x;
    int gmt = gridDim.y;
    int gw = 8 * gmt;
    int grp = lin / gw;
    int rem = lin - grp * gw;
    int bn = grp * 8 + (rem & 7);
    int bm = rem >> 3;
    int m0 = bm * BM;
    int n0 = bn * BN;
    int wave = t >> 6, lane = t & 63;
    int wm = (wave >> 1) * 64, wn = (wave & 1) * 64;
    int lr = lane & 15;
    int quad = lane >> 4;

    // global_load_lds staging: wave w stages rows [16w,16w+16) and [64+16w, 64+16w+16)
    int srow = lane >> 2;        // 0..15
    int scol = (lane & 3) * 8;   // 0,8,16,24 (bf16)
    const bf16_t* ag = A + (size_t)(m0 + wave * 16 + srow) * K + scol;
    const bf16_t* bg = Bt + (size_t)(n0 + wave * 16 + srow) * K + scol;
    bf16_t* asl = As + wave * 16 * BKK;
    bf16_t* bsl = Bs + wave * 16 * BKK;
    const size_t rowskip = (size_t)64 * K;

    f32x4 acc[4][4];
#pragma unroll
    for (int mi = 0; mi < 4; mi++)
#pragma unroll
        for (int ni = 0; ni < 4; ni++) acc[mi][ni] = 0.f;

    for (int k0 = 0; k0 < K; k0 += BKK) {
        gl2lds16(ag + k0, asl);
        gl2lds16(ag + k0 + rowskip, asl + 64 * BKK);
        gl2lds16(bg + k0, bsl);
        gl2lds16(bg + k0 + rowskip, bsl + 64 * BKK);
        __syncthreads();
        bf16x8 af[4], bfv[4];
#pragma unroll
        for (int mi = 0; mi < 4; mi++)
            af[mi] = *reinterpret_cast<const bf16x8*>(&As[(wm + mi * 16 + lr) * BKK + quad * 8]);
#pragma unroll
        for (int ni = 0; ni < 4; ni++)
            bfv[ni] = *reinterpret_cast<const bf16x8*>(&Bs[(wn + ni * 16 + lr) * BKK + quad * 8]);
#pragma unroll
        for (int mi = 0; mi < 4; mi++)
#pragma unroll
            for (int ni = 0; ni < 4; ni++)
                acc[mi][ni] = __builtin_amdgcn_mfma_f32_16x16x32_bf16(af[mi], bfv[ni],
                                                                      acc[mi][ni], 0, 0, 0);
        __syncthreads();
    }
    if constexpr (EPI == 3) {
        if (n0 + wn < 2048) {
            // RoPE: feature i pairs with i+32 within a head (head = 64 cols = one wn tile)
            const float kfreq = -0.41524101186f;  // -log2(10000)/32
#pragma unroll
            for (int mi = 0; mi < 4; mi++) {
#pragma unroll
                for (int j = 0; j < 4; j++) {
                    int gm = m0 + wm + mi * 16 + quad * 4 + j;
                    float sf = (float)(gm & 2047);  // position (S=2048)
#pragma unroll
                    for (int ni = 0; ni < 2; ni++) {
                        int ip = ni * 16 + lr;
                        float freq = exp2f((float)ip * kfreq);
                        float ang = sf * freq;
                        float sn, cs;
                        __sincosf(ang, &sn, &cs);
                        float x1 = acc[mi][ni][j], x2 = acc[mi][ni + 2][j];
                        size_t idx = (size_t)gm * N + n0 + wn + ni * 16 + lr;
                        Cb[idx] = (bf16_t)(x1 * cs - x2 * sn);
                        Cb[idx + 32] = (bf16_t)(x2 * cs + x1 * sn);
                    }
                }
            }
        } else {
#pragma unroll
            for (int mi = 0; mi < 4; mi++)
#pragma unroll
                for (int ni = 0; ni < 4; ni++)
#pragma unroll
                    for (int j = 0; j < 4; j++) {
                        int gm = m0 + wm + mi * 16 + quad * 4 + j;
                        size_t idx = (size_t)gm * N + n0 + wn + ni * 16 + lr;
                        Cb[idx] = (bf16_t)acc[mi][ni][j];
                    }
        }
    } else {
#pragma unroll
        for (int mi = 0; mi < 4; mi++) {
#pragma unroll
            for (int ni = 0; ni < 4; ni++) {
#pragma unroll
                for (int j = 0; j < 4; j++) {
                    int gm = m0 + wm + mi * 16 + quad * 4 + j;
                    int gn = n0 + wn + ni * 16 + lr;
                    size_t idx = (size_t)gm * N + gn;
                    float val = acc[mi][ni][j];
                    if constexpr (EPI == 0) {
                        Cf[idx] = val;
                    } else if constexpr (EPI == 1) {
                        Cf[idx] = val + aux[idx];
                    } else if constexpr (EPI == 2) {
                        float a = (float)auxb[idx];
                        float sl = a / (1.0f + __expf(-a));
                        Cb[idx] = (bf16_t)(sl * val);
                    } else {  // EPI 4
                        Cb[idx] = (bf16_t)val;
                    }
                }
            }
        }
    }
}

// ---------------- V transpose: qkv v-section [B*S, 3072] -> vt [B, H, 64, S] ----------------
__global__ void transpose_v_kernel(const bf16_t* __restrict__ v, bf16_t* __restrict__ vt,
                                   int S, int stride) {
    __shared__ bf16_t tile[64][66];
    int t = threadIdx.x;
    int s0 = blockIdx.x * 64;
    int h = blockIdx.y, b = blockIdx.z;
#pragma unroll
    for (int i = 0; i < 2; i++) {
        int c = t + i * 256;
        int ss = c >> 3, d8 = (c & 7) * 8;
        bf16x8 val = *reinterpret_cast<const bf16x8*>(
            &v[(size_t)(b * S + s0 + ss) * stride + h * 64 + d8]);
#pragma unroll
        for (int jj = 0; jj < 8; jj++) tile[ss][d8 + jj] = val[jj];
    }
    __syncthreads();
#pragma unroll
    for (int i = 0; i < 2; i++) {
        int c = t + i * 256;
        int d = c >> 3, s8 = (c & 7) * 8;
        bf16x8 o;
#pragma unroll
        for (int jj = 0; jj < 8; jj++) o[jj] = tile[s8 + jj][d];
        *reinterpret_cast<bf16x8*>(&vt[(((size_t)(b * 16 + h)) * 64 + d) * S + s0 + s8]) = o;
    }
}

// ---------------- MFMA sliding-window attention ----------------
// grid (S/64, H, B), 256 threads = 4 waves; each wave owns a 16-query tile.
// qkv: bf16 [B*S, 3072] (q | k | v, RoPE applied to q,k). vt: bf16 [B,H,64,S].
#define PSTR 40
#define QKVS 3072
__global__ __launch_bounds__(256, 2) void attn_kernel(const bf16_t* __restrict__ qkv,
                                                      const bf16_t* __restrict__ vt,
                                                      bf16_t* __restrict__ ctx, int S) {
    __shared__ __align__(16) bf16_t Pbuf[4][16 * PSTR];
    int t = threadIdx.x;
    int wave = t >> 6, lane = t & 63;
    int col = lane & 15, quad = lane >> 4;
    int h = blockIdx.y, b = blockIdx.z;
    int q0 = blockIdx.x * 64 + wave * 16;

    const bf16_t* qrow = qkv + (size_t)(b * S + q0 + col) * QKVS + h * 64;
    bf16x8 aq0 = *reinterpret_cast<const bf16x8*>(qrow + quad * 8);
    bf16x8 aq1 = *reinterpret_cast<const bf16x8*>(qrow + 32 + quad * 8);

    int jbase = q0 - 256;
    f32x4 sc[18];
#pragma unroll
    for (int kt = 0; kt < 18; kt++) {
        int j = jbase + kt * 16 + col;
        int jc = j < 0 ? 0 : (j > S - 1 ? S - 1 : j);
        const bf16_t* krow = qkv + (size_t)(b * S + jc) * QKVS + 1024 + h * 64;
        bf16x8 bk0 = *reinterpret_cast<const bf16x8*>(krow + quad * 8);
        bf16x8 bk1 = *reinterpret_cast<const bf16x8*>(krow + 32 + quad * 8);
        f32x4 c0 = {0.f, 0.f, 0.f, 0.f};
        c0 = __builtin_amdgcn_mfma_f32_16x16x32_bf16(aq0, bk0, c0, 0, 0, 0);
        c0 = __builtin_amdgcn_mfma_f32_16x16x32_bf16(aq1, bk1, c0, 0, 0, 0);
        sc[kt] = c0;
    }
#pragma unroll
    for (int kt = 0; kt < 18; kt++) {
#pragma unroll
        for (int jj = 0; jj < 4; jj++) {
            int qq = quad * 4 + jj;
            int j = jbase + kt * 16 + col;
            int rel = (q0 + qq) - j;
            bool ok = (j >= 0) && (rel >= 0) && (rel < 256);
            sc[kt][jj] = ok ? sc[kt][jj] * 0.125f : -1e30f;
        }
    }
    float sminv[4];
#pragma unroll
    for (int jj = 0; jj < 4; jj++) {
        float m = -1e30f;
#pragma unroll
        for (int kt = 0; kt < 18; kt++) m = fmaxf(m, sc[kt][jj]);
#pragma unroll
        for (int o = 1; o < 16; o <<= 1) m = fmaxf(m, __shfl_xor(m, o));
        float s = 0.f;
#pragma unroll
        for (int kt = 0; kt < 18; kt++) {
            float p = __expf(sc[kt][jj] - m);
            sc[kt][jj] = p;
            s += p;
        }
#pragma unroll
        for (int o = 1; o < 16; o <<= 1) s += __shfl_xor(s, o);
        sminv[jj] = 1.0f / s;
    }
    f32x4 o[4];
#pragma unroll
    for (int n = 0; n < 4; n++) o[n] = 0.f;
    bf16_t* myP = Pbuf[wave];
    const bf16_t* vplane = vt + ((size_t)(b * 16 + h)) * 64 * S;
#pragma unroll
    for (int c = 0; c < 9; c++) {
#pragma unroll
        for (int half = 0; half < 2; half++) {
            int kt = 2 * c + half;
#pragma unroll
            for (int jj = 0; jj < 4; jj++) {
                int qq = quad * 4 + jj;
                myP[qq * PSTR + half * 16 + col] = (bf16_t)(sc[kt][jj] * sminv[jj]);
            }
        }
        bf16x8 ap = *reinterpret_cast<const bf16x8*>(myP + col * PSTR + quad * 8);
        int key0 = jbase + c * 32 + quad * 8;
        int kc = key0 < 0 ? 0 : (key0 > S - 8 ? S - 8 : key0);
#pragma unroll
        for (int n = 0; n < 4; n++) {
            bf16x8 bv = *reinterpret_cast<const bf16x8*>(vplane + ((size_t)(n * 16 + col)) * S + kc);
            o[n] = __builtin_amdgcn_mfma_f32_16x16x32_bf16(ap, bv, o[n], 0, 0, 0);
        }
    }
#pragma unroll
    for (int n = 0; n < 4; n++)
#pragma unroll
        for (int jj = 0; jj < 4; jj++) {
            int qq = quad * 4 + jj;
            ctx[((size_t)(b * S + q0 + qq) * 16 + h) * 64 + n * 16 + col] = (bf16_t)o[n][jj];
        }
}

// ---------------- launch ----------------
extern "C" void kernel_launch(void* const* d_in, const int* in_sizes, int n_in,
                              void* d_out, int out_size, void* d_ws, size_t ws_size,
                              hipStream_t stream) {
    const float* hs   = (const float*)d_in[0];
    const float* wq   = (const float*)d_in[1];
    const float* wk   = (const float*)d_in[2];
    const float* wv   = (const float*)d_in[3];
    const float* wo   = (const float*)d_in[4];
    const float* w1   = (const float*)d_in[5];
    const float* w2   = (const float*)d_in[6];
    const float* w3   = (const float*)d_in[7];
    const float* ln1g = (const float*)d_in[8];
    const float* ln1b = (const float*)d_in[9];
    const float* ln2g = (const float*)d_in[10];
    const float* ln2b = (const float*)d_in[11];
    float* out = (float*)d_out;

    const int B = 2, S = 2048, D = 1024, I = 4096;
    const int BS = B * S;

    char* ws = (char*)d_ws;
    const size_t MB = 1024 * 1024;
    // wq_t/wk_t/wv_t contiguous -> one [3072,1024] B matrix for the fused QKV GEMM
    bf16_t* wq_t = (bf16_t*)(ws + 0 * MB);    // 2MB
    bf16_t* wk_t = (bf16_t*)(ws + 2 * MB);    // 2MB
    bf16_t* wv_t = (bf16_t*)(ws + 4 * MB);    // 2MB
    bf16_t* wo_t = (bf16_t*)(ws + 6 * MB);    // 2MB
    bf16_t* w1_t = (bf16_t*)(ws + 8 * MB);    // 8MB
    bf16_t* w3_t = (bf16_t*)(ws + 16 * MB);   // 8MB
    bf16_t* w2_t = (bf16_t*)(ws + 24 * MB);   // 8MB
    bf16_t* x_b  = (bf16_t*)(ws + 32 * MB);   // 8MB
    float*  hid  = (float*)(ws + 40 * MB);    // 16MB
    bf16_t* x2_b = (bf16_t*)(ws + 56 * MB);   // 8MB
    bf16_t* qkvb = (bf16_t*)(ws + 64 * MB);   // 24MB [BS,3072]
    bf16_t* vt   = (bf16_t*)(ws + 88 * MB);   // 8MB
    bf16_t* ctxb = (bf16_t*)(ws + 96 * MB);   // 8MB
    bf16_t* h1b  = (bf16_t*)(ws + 64 * MB);   // 32MB, aliases qkvb/vt (dead post-attn)
    bf16_t* hbuf = (bf16_t*)(ws + 96 * MB);   // 32MB, aliases ctxb (dead post-Wo); end 128MB

    dim3 tb(256);
    transpose_cvt_kernel<<<dim3(D / 32, D / 32), tb, 0, stream>>>(wq, wq_t, D, D);
    transpose_cvt_kernel<<<dim3(D / 32, D / 32), tb, 0, stream>>>(wk, wk_t, D, D);
    transpose_cvt_kernel<<<dim3(D / 32, D / 32), tb, 0, stream>>>(wv, wv_t, D, D);
    transpose_cvt_kernel<<<dim3(D / 32, D / 32), tb, 0, stream>>>(wo, wo_t, D, D);
    transpose_cvt_kernel<<<dim3(I / 32, D / 32), tb, 0, stream>>>(w1, w1_t, D, I);
    transpose_cvt_kernel<<<dim3(I / 32, D / 32), tb, 0, stream>>>(w3, w3_t, D, I);
    transpose_cvt_kernel<<<dim3(D / 32, I / 32), tb, 0, stream>>>(w2, w2_t, I, D);

    ln_kernel<<<BS, tb, 0, stream>>>(hs, ln1g, ln1b, x_b, D);

    // fused QKV GEMM: Bt = [wq_t; wk_t; wv_t] (3072 rows), RoPE fused for q,k cols
    gemm_kernel<3><<<dim3(3072 / BN, BS / BM), tb, 0, stream>>>(x_b, wq_t, nullptr, nullptr,
                                                                nullptr, qkvb, BS, 3072, D);

    transpose_v_kernel<<<dim3(S / 64, 16, B), tb, 0, stream>>>(qkvb + 2048, vt, S, QKVS);

    attn_kernel<<<dim3(S / 64, 16, B), tb, 0, stream>>>(qkvb, vt, ctxb, S);

    gemm_kernel<1><<<dim3(D / BN, BS / BM), tb, 0, stream>>>(ctxb, wo_t, hid, hs, nullptr, nullptr, BS, D, D);

    ln_kernel<<<BS, tb, 0, stream>>>(hid, ln2g, ln2b, x2_b, D);

    gemm_kernel<4><<<dim3(I / BN, BS / BM), tb, 0, stream>>>(x2_b, w1_t, nullptr, nullptr, nullptr, h1b, BS, I, D);
    gemm_kernel<2><<<dim3(I / BN, BS / BM), tb, 0, stream>>>(x2_b, w3_t, nullptr, nullptr, h1b, hbuf, BS, I, D);
    gemm_kernel<1><<<dim3(D / BN, BS / BM), tb, 0, stream>>>(hbuf, w2_t, out, hid, nullptr, nullptr, BS, D, I);
}

// Round 5
// 420.334 us; speedup vs baseline: 2.3932x; 1.0217x over previous
//
#include <hip/hip_runtime.h>
#include <hip/hip_bf16.h>

typedef __bf16 bf16_t;
typedef __bf16 bf16x4 __attribute__((ext_vector_type(4)));
typedef __bf16 bf16x8 __attribute__((ext_vector_type(8)));
typedef float f32x4 __attribute__((ext_vector_type(4)));
typedef float f32x16 __attribute__((ext_vector_type(16)));

#define LN_EPS 1e-6f

__device__ __forceinline__ void gl2lds16(const void* g, void* l) {
    __builtin_amdgcn_global_load_lds(
        (const __attribute__((address_space(1))) void*)g,
        (__attribute__((address_space(3))) void*)l, 16, 0, 0);
}

// ---------------- transpose + fp32->bf16 convert (weights) ----------------
__global__ void transpose_cvt_kernel(const float* __restrict__ in, bf16_t* __restrict__ out,
                                     int R, int C) {
    __shared__ float tile[32][33];
    int tx = threadIdx.x & 31;
    int ty = threadIdx.x >> 5;
    int r0 = blockIdx.y * 32;
    int c0 = blockIdx.x * 32;
#pragma unroll
    for (int i = 0; i < 4; i++) {
        int r = ty + i * 8;
        tile[r][tx] = in[(size_t)(r0 + r) * C + (c0 + tx)];
    }
    __syncthreads();
#pragma unroll
    for (int i = 0; i < 4; i++) {
        int r = ty + i * 8;
        out[(size_t)(c0 + r) * R + (r0 + tx)] = (bf16_t)tile[tx][r];
    }
}

// ---------------- LayerNorm (fp32 in) -> bf16 out ----------------
__global__ void ln_kernel(const float* __restrict__ x, const float* __restrict__ g,
                          const float* __restrict__ bb, bf16_t* __restrict__ out, int D) {
    int row = blockIdx.x;
    int t = threadIdx.x;
    const float4* xr = reinterpret_cast<const float4*>(x + (size_t)row * D);
    float4 v = xr[t];
    float s = v.x + v.y + v.z + v.w;
    __shared__ float sbuf[4];
    __shared__ float sbuf2[4];
    int wave = t >> 6, lane = t & 63;
#pragma unroll
    for (int o = 32; o > 0; o >>= 1) s += __shfl_xor(s, o);
    if (lane == 0) sbuf[wave] = s;
    __syncthreads();
    float mean = (sbuf[0] + sbuf[1] + sbuf[2] + sbuf[3]) / (float)D;
    float d0 = v.x - mean, d1 = v.y - mean, d2 = v.z - mean, d3 = v.w - mean;
    float sq = d0 * d0 + d1 * d1 + d2 * d2 + d3 * d3;
#pragma unroll
    for (int o = 32; o > 0; o >>= 1) sq += __shfl_xor(sq, o);
    if (lane == 0) sbuf2[wave] = sq;
    __syncthreads();
    float var = (sbuf2[0] + sbuf2[1] + sbuf2[2] + sbuf2[3]) / (float)D;
    float inv = rsqrtf(var + LN_EPS);
    float4 gv = reinterpret_cast<const float4*>(g)[t];
    float4 bv = reinterpret_cast<const float4*>(bb)[t];
    bf16_t* o0 = out + (size_t)row * D + t * 4;
    o0[0] = (bf16_t)(d0 * inv * gv.x + bv.x);
    o0[1] = (bf16_t)(d1 * inv * gv.y + bv.y);
    o0[2] = (bf16_t)(d2 * inv * gv.z + bv.z);
    o0[3] = (bf16_t)(d3 * inv * gv.w + bv.w);
}

// ---------------- 16x16 MFMA GEMM (kept for Wo): Cf = acc + aux ----------------
#define BM 128
#define BN 128
#define BKK 32

template <int EPI>
__launch_bounds__(256, 2) __global__
void gemm_kernel(const bf16_t* __restrict__ A, const bf16_t* __restrict__ Bt,
                 float* __restrict__ Cf, const float* __restrict__ aux,
                 const bf16_t* __restrict__ auxb, bf16_t* __restrict__ Cb,
                 int M, int N, int K) {
    __shared__ __align__(16) bf16_t As[BM * BKK];
    __shared__ __align__(16) bf16_t Bs[BN * BKK];
    int t = threadIdx.x;
    int lin = blockIdx.y * gridDim.x + blockIdx.x;
    int gmt = gridDim.y;
    int gw = 8 * gmt;
    int grp = lin / gw;
    int rem = lin - grp * gw;
    int bn = grp * 8 + (rem & 7);
    int bm = rem >> 3;
    int m0 = bm * BM;
    int n0 = bn * BN;
    int wave = t >> 6, lane = t & 63;
    int wm = (wave >> 1) * 64, wn = (wave & 1) * 64;
    int lr = lane & 15;
    int quad = lane >> 4;

    int srow = lane >> 2;
    int scol = (lane & 3) * 8;
    const bf16_t* ag = A + (size_t)(m0 + wave * 16 + srow) * K + scol;
    const bf16_t* bg = Bt + (size_t)(n0 + wave * 16 + srow) * K + scol;
    bf16_t* asl = As + wave * 16 * BKK;
    bf16_t* bsl = Bs + wave * 16 * BKK;
    const size_t rowskip = (size_t)64 * K;

    f32x4 acc[4][4];
#pragma unroll
    for (int mi = 0; mi < 4; mi++)
#pragma unroll
        for (int ni = 0; ni < 4; ni++) acc[mi][ni] = 0.f;

    for (int k0 = 0; k0 < K; k0 += BKK) {
        gl2lds16(ag + k0, asl);
        gl2lds16(ag + k0 + rowskip, asl + 64 * BKK);
        gl2lds16(bg + k0, bsl);
        gl2lds16(bg + k0 + rowskip, bsl + 64 * BKK);
        __syncthreads();
        bf16x8 af[4], bfv[4];
#pragma unroll
        for (int mi = 0; mi < 4; mi++)
            af[mi] = *reinterpret_cast<const bf16x8*>(&As[(wm + mi * 16 + lr) * BKK + quad * 8]);
#pragma unroll
        for (int ni = 0; ni < 4; ni++)
            bfv[ni] = *reinterpret_cast<const bf16x8*>(&Bs[(wn + ni * 16 + lr) * BKK + quad * 8]);
#pragma unroll
        for (int mi = 0; mi < 4; mi++)
#pragma unroll
            for (int ni = 0; ni < 4; ni++)
                acc[mi][ni] = __builtin_amdgcn_mfma_f32_16x16x32_bf16(af[mi], bfv[ni],
                                                                      acc[mi][ni], 0, 0, 0);
        __syncthreads();
    }
#pragma unroll
    for (int mi = 0; mi < 4; mi++) {
#pragma unroll
        for (int ni = 0; ni < 4; ni++) {
#pragma unroll
            for (int j = 0; j < 4; j++) {
                int gm = m0 + wm + mi * 16 + quad * 4 + j;
                int gn = n0 + wn + ni * 16 + lr;
                size_t idx = (size_t)gm * N + gn;
                float val = acc[mi][ni][j];
                if constexpr (EPI == 1) {
                    Cf[idx] = val + aux[idx];
                }
            }
        }
    }
}

// ---------------- 32x32 MFMA GEMM: tile 256x128, wave = 64x128, BK=32 ----------------
// A [M,K] row-major (lda), Bt [N,K] row-major (ldb). grid: x=M-tiles, y=N-tiles, z=K-chunks.
// EPI 2: Cb = silu(auxb)*acc (bf16)
// EPI 3: QKV fused RoPE (cols<2048 rope, else plain), N must be 3072
// EPI 4: Cb = acc (bf16)
// EPI 5: Cb[z*M*N + ...] = acc (bf16 partial, split-K)
#define G2_BM 256
#define G2_BN 128
#define G2_BK 32

template <int EPI>
__launch_bounds__(256, 2) __global__
void gemm2_kernel(const bf16_t* __restrict__ A, const bf16_t* __restrict__ Bt,
                  const bf16_t* __restrict__ auxb, bf16_t* __restrict__ Cb,
                  int M, int N, int K, int lda, int ldb) {
    __shared__ __align__(16) bf16_t As[G2_BM * G2_BK];  // 16 KB
    __shared__ __align__(16) bf16_t Bs[G2_BN * G2_BK];  // 8 KB
    int t = threadIdx.x;
    int wave = t >> 6, lane = t & 63;
    int m0 = blockIdx.x * G2_BM;
    int n0 = blockIdx.y * G2_BN;
    int koff = blockIdx.z * K;

    // staging: wave stages A rows [64w,64w+64) (4 instrs), B rows [32w,32w+32) (2 instrs)
    // XOR-swizzle: LDS slot (r, q') holds global (r, q' ^ (r&3)), q = 8-elem group in BK=32
    int sr = lane >> 2;                      // 0..15 row within 16-row chunk
    int sq = (lane & 3) ^ (sr & 3);          // swizzled source k-quad
    const bf16_t* ag = A + (size_t)(m0 + 64 * wave + sr) * lda + koff + sq * 8;
    const bf16_t* bg = Bt + (size_t)(n0 + 32 * wave + sr) * ldb + koff + sq * 8;
    bf16_t* asl = As + (64 * wave) * G2_BK;
    bf16_t* bsl = Bs + (32 * wave) * G2_BK;

    f32x16 acc[2][4];
#pragma unroll
    for (int mi = 0; mi < 2; mi++)
#pragma unroll
        for (int ni = 0; ni < 4; ni++) acc[mi][ni] = 0.f;

    int l31 = lane & 31;
    int lh = lane >> 5;       // k-half selector
    int lx = lane & 3;        // row&3 for swizzle (rows differ by 32-mult)

    for (int k0 = 0; k0 < K; k0 += G2_BK) {
#pragma unroll
        for (int i = 0; i < 4; i++)
            gl2lds16(ag + k0 + (size_t)(16 * i) * lda, asl + (16 * i) * G2_BK);
#pragma unroll
        for (int i = 0; i < 2; i++)
            gl2lds16(bg + k0 + (size_t)(16 * i) * ldb, bsl + (16 * i) * G2_BK);
        __syncthreads();
#pragma unroll
        for (int s = 0; s < 2; s++) {
            int q = 2 * s + lh;
            bf16x8 af[2], bfv[4];
#pragma unroll
            for (int mi = 0; mi < 2; mi++) {
                int row = 64 * wave + mi * 32 + l31;
                af[mi] = *reinterpret_cast<const bf16x8*>(&As[row * G2_BK + (q ^ lx) * 8]);
            }
#pragma unroll
            for (int ni = 0; ni < 4; ni++) {
                int row = ni * 32 + l31;
                bfv[ni] = *reinterpret_cast<const bf16x8*>(&Bs[row * G2_BK + (q ^ lx) * 8]);
            }
#pragma unroll
            for (int mi = 0; mi < 2; mi++)
#pragma unroll
                for (int ni = 0; ni < 4; ni++)
                    acc[mi][ni] = __builtin_amdgcn_mfma_f32_32x32x16_bf16(af[mi], bfv[ni],
                                                                          acc[mi][ni], 0, 0, 0);
        }
        __syncthreads();
    }

    // C/D layout: col = lane&31, row = (reg&3) + 8*(reg>>2) + 4*(lane>>5)
    if constexpr (EPI == 3) {
        const float kfreq = -0.41524101186f;  // -log2(10000)/32
        bool do_rope = (n0 < 2048);
#pragma unroll
        for (int mi = 0; mi < 2; mi++) {
#pragma unroll
            for (int reg = 0; reg < 16; reg++) {
                int rrow = (reg & 3) + 8 * (reg >> 2) + 4 * lh;
                int gm = m0 + 64 * wave + mi * 32 + rrow;
                if (do_rope) {
                    float sf = (float)(gm & 2047);
                    float freq = exp2f((float)l31 * kfreq);
                    float ang = sf * freq;
                    float sn, cs;
                    __sincosf(ang, &sn, &cs);
#pragma unroll
                    for (int p = 0; p < 2; p++) {
                        float x1 = acc[mi][2 * p][reg];
                        float x2 = acc[mi][2 * p + 1][reg];
                        size_t idx = (size_t)gm * N + n0 + p * 64 + l31;
                        Cb[idx] = (bf16_t)(x1 * cs - x2 * sn);
                        Cb[idx + 32] = (bf16_t)(x2 * cs + x1 * sn);
                    }
                } else {
#pragma unroll
                    for (int ni = 0; ni < 4; ni++) {
                        size_t idx = (size_t)gm * N + n0 + ni * 32 + l31;
                        Cb[idx] = (bf16_t)acc[mi][ni][reg];
                    }
                }
            }
        }
    } else {
        size_t outoff = (EPI == 5) ? (size_t)blockIdx.z * M * N : 0;
#pragma unroll
        for (int mi = 0; mi < 2; mi++) {
#pragma unroll
            for (int reg = 0; reg < 16; reg++) {
                int rrow = (reg & 3) + 8 * (reg >> 2) + 4 * lh;
                int gm = m0 + 64 * wave + mi * 32 + rrow;
#pragma unroll
                for (int ni = 0; ni < 4; ni++) {
                    int gn = n0 + ni * 32 + l31;
                    size_t idx = (size_t)gm * N + gn;
                    float val = acc[mi][ni][reg];
                    if constexpr (EPI == 2) {
                        float a = (float)auxb[idx];
                        float sl = a / (1.0f + __expf(-a));
                        Cb[idx] = (bf16_t)(sl * val);
                    } else if constexpr (EPI == 4) {
                        Cb[idx] = (bf16_t)val;
                    } else if constexpr (EPI == 5) {
                        Cb[outoff + idx] = (bf16_t)val;
                    }
                }
            }
        }
    }
}

// ---------------- split-K reduce + residual: out = hid + sum_c partial[c] ----------------
__global__ void reduce4_kernel(const bf16_t* __restrict__ p, const float* __restrict__ hid,
                               float* __restrict__ out, int n4) {
    int i = blockIdx.x * 256 + threadIdx.x;
    if (i >= n4) return;
    size_t i4 = (size_t)i * 4;
    float4 h = *reinterpret_cast<const float4*>(hid + i4);
    const size_t stride = (size_t)4096 * 1024;
#pragma unroll
    for (int c = 0; c < 4; c++) {
        bf16x4 a = *reinterpret_cast<const bf16x4*>(p + c * stride + i4);
        h.x += (float)a[0];
        h.y += (float)a[1];
        h.z += (float)a[2];
        h.w += (float)a[3];
    }
    *reinterpret_cast<float4*>(out + i4) = h;
}

// ---------------- V transpose: qkv v-section [B*S, 3072] -> vt [B, H, 64, S] ----------------
__global__ void transpose_v_kernel(const bf16_t* __restrict__ v, bf16_t* __restrict__ vt,
                                   int S, int stride) {
    __shared__ bf16_t tile[64][66];
    int t = threadIdx.x;
    int s0 = blockIdx.x * 64;
    int h = blockIdx.y, b = blockIdx.z;
#pragma unroll
    for (int i = 0; i < 2; i++) {
        int c = t + i * 256;
        int ss = c >> 3, d8 = (c & 7) * 8;
        bf16x8 val = *reinterpret_cast<const bf16x8*>(
            &v[(size_t)(b * S + s0 + ss) * stride + h * 64 + d8]);
#pragma unroll
        for (int jj = 0; jj < 8; jj++) tile[ss][d8 + jj] = val[jj];
    }
    __syncthreads();
#pragma unroll
    for (int i = 0; i < 2; i++) {
        int c = t + i * 256;
        int d = c >> 3, s8 = (c & 7) * 8;
        bf16x8 o;
#pragma unroll
        for (int jj = 0; jj < 8; jj++) o[jj] = tile[s8 + jj][d];
        *reinterpret_cast<bf16x8*>(&vt[(((size_t)(b * 16 + h)) * 64 + d) * S + s0 + s8]) = o;
    }
}

// ---------------- MFMA sliding-window attention ----------------
#define PSTR 40
#define QKVS 3072
__global__ __launch_bounds__(256, 2) void attn_kernel(const bf16_t* __restrict__ qkv,
                                                      const bf16_t* __restrict__ vt,
                                                      bf16_t* __restrict__ ctx, int S) {
    __shared__ __align__(16) bf16_t Pbuf[4][16 * PSTR];
    int t = threadIdx.x;
    int wave = t >> 6, lane = t & 63;
    int col = lane & 15, quad = lane >> 4;
    int h = blockIdx.y, b = blockIdx.z;
    int q0 = blockIdx.x * 64 + wave * 16;

    const bf16_t* qrow = qkv + (size_t)(b * S + q0 + col) * QKVS + h * 64;
    bf16x8 aq0 = *reinterpret_cast<const bf16x8*>(qrow + quad * 8);
    bf16x8 aq1 = *reinterpret_cast<const bf16x8*>(qrow + 32 + quad * 8);

    int jbase = q0 - 256;
    f32x4 sc[18];
#pragma unroll
    for (int kt = 0; kt < 18; kt++) {
        int j = jbase + kt * 16 + col;
        int jc = j < 0 ? 0 : (j > S - 1 ? S - 1 : j);
        const bf16_t* krow = qkv + (size_t)(b * S + jc) * QKVS + 1024 + h * 64;
        bf16x8 bk0 = *reinterpret_cast<const bf16x8*>(krow + quad * 8);
        bf16x8 bk1 = *reinterpret_cast<const bf16x8*>(krow + 32 + quad * 8);
        f32x4 c0 = {0.f, 0.f, 0.f, 0.f};
        c0 = __builtin_amdgcn_mfma_f32_16x16x32_bf16(aq0, bk0, c0, 0, 0, 0);
        c0 = __builtin_amdgcn_mfma_f32_16x16x32_bf16(aq1, bk1, c0, 0, 0, 0);
        sc[kt] = c0;
    }
#pragma unroll
    for (int kt = 0; kt < 18; kt++) {
#pragma unroll
        for (int jj = 0; jj < 4; jj++) {
            int qq = quad * 4 + jj;
            int j = jbase + kt * 16 + col;
            int rel = (q0 + qq) - j;
            bool ok = (j >= 0) && (rel >= 0) && (rel < 256);
            sc[kt][jj] = ok ? sc[kt][jj] * 0.125f : -1e30f;
        }
    }
    float sminv[4];
#pragma unroll
    for (int jj = 0; jj < 4; jj++) {
        float m = -1e30f;
#pragma unroll
        for (int kt = 0; kt < 18; kt++) m = fmaxf(m, sc[kt][jj]);
#pragma unroll
        for (int o = 1; o < 16; o <<= 1) m = fmaxf(m, __shfl_xor(m, o));
        float s = 0.f;
#pragma unroll
        for (int kt = 0; kt < 18; kt++) {
            float p = __expf(sc[kt][jj] - m);
            sc[kt][jj] = p;
            s += p;
        }
#pragma unroll
        for (int o = 1; o < 16; o <<= 1) s += __shfl_xor(s, o);
        sminv[jj] = 1.0f / s;
    }
    f32x4 o[4];
#pragma unroll
    for (int n = 0; n < 4; n++) o[n] = 0.f;
    bf16_t* myP = Pbuf[wave];
    const bf16_t* vplane = vt + ((size_t)(b * 16 + h)) * 64 * S;
#pragma unroll
    for (int c = 0; c < 9; c++) {
#pragma unroll
        for (int half = 0; half < 2; half++) {
            int kt = 2 * c + half;
#pragma unroll
            for (int jj = 0; jj < 4; jj++) {
                int qq = quad * 4 + jj;
                myP[qq * PSTR + half * 16 + col] = (bf16_t)(sc[kt][jj] * sminv[jj]);
            }
        }
        bf16x8 ap = *reinterpret_cast<const bf16x8*>(myP + col * PSTR + quad * 8);
        int key0 = jbase + c * 32 + quad * 8;
        int kc = key0 < 0 ? 0 : (key0 > S - 8 ? S - 8 : key0);
#pragma unroll
        for (int n = 0; n < 4; n++) {
            bf16x8 bv = *reinterpret_cast<const bf16x8*>(vplane + ((size_t)(n * 16 + col)) * S + kc);
            o[n] = __builtin_amdgcn_mfma_f32_16x16x32_bf16(ap, bv, o[n], 0, 0, 0);
        }
    }
#pragma unroll
    for (int n = 0; n < 4; n++)
#pragma unroll
        for (int jj = 0; jj < 4; jj++) {
            int qq = quad * 4 + jj;
            ctx[((size_t)(b * S + q0 + qq) * 16 + h) * 64 + n * 16 + col] = (bf16_t)o[n][jj];
        }
}

// ---------------- launch ----------------
extern "C" void kernel_launch(void* const* d_in, const int* in_sizes, int n_in,
                              void* d_out, int out_size, void* d_ws, size_t ws_size,
                              hipStream_t stream) {
    const float* hs   = (const float*)d_in[0];
    const float* wq   = (const float*)d_in[1];
    const float* wk   = (const float*)d_in[2];
    const float* wv   = (const float*)d_in[3];
    const float* wo   = (const float*)d_in[4];
    const float* w1   = (const float*)d_in[5];
    const float* w2   = (const float*)d_in[6];
    const float* w3   = (const float*)d_in[7];
    const float* ln1g = (const float*)d_in[8];
    const float* ln1b = (const float*)d_in[9];
    const float* ln2g = (const float*)d_in[10];
    const float* ln2b = (const float*)d_in[11];
    float* out = (float*)d_out;

    const int B = 2, S = 2048, D = 1024, I = 4096;
    const int BS = B * S;

    char* ws = (char*)d_ws;
    const size_t MB = 1024 * 1024;
    // wq_t/wk_t/wv_t contiguous -> one [3072,1024] B matrix for fused QKV
    bf16_t* wq_t = (bf16_t*)(ws + 0 * MB);    // 2MB
    bf16_t* wk_t = (bf16_t*)(ws + 2 * MB);    // 2MB
    bf16_t* wv_t = (bf16_t*)(ws + 4 * MB);    // 2MB
    bf16_t* wo_t = (bf16_t*)(ws + 6 * MB);    // 2MB
    bf16_t* w1_t = (bf16_t*)(ws + 8 * MB);    // 8MB
    bf16_t* w3_t = (bf16_t*)(ws + 16 * MB);   // 8MB
    bf16_t* w2_t = (bf16_t*)(ws + 24 * MB);   // 8MB
    bf16_t* x_b  = (bf16_t*)(ws + 32 * MB);   // 8MB
    float*  hid  = (float*)(ws + 40 * MB);    // 16MB
    bf16_t* x2_b = (bf16_t*)(ws + 56 * MB);   // 8MB
    bf16_t* qkvb = (bf16_t*)(ws + 64 * MB);   // 24MB [BS,3072]
    bf16_t* vt   = (bf16_t*)(ws + 88 * MB);   // 8MB
    bf16_t* ctxb = (bf16_t*)(ws + 96 * MB);   // 8MB
    bf16_t* h1b  = (bf16_t*)(ws + 64 * MB);   // 32MB, aliases qkvb/vt (dead post-attn)
    bf16_t* hbuf = (bf16_t*)(ws + 96 * MB);   // 32MB, aliases ctxb (dead post-Wo)
    bf16_t* pker = (bf16_t*)(ws + 64 * MB);   // 32MB, aliases h1b (dead post-W3); 4x 8MB partials

    dim3 tb(256);
    transpose_cvt_kernel<<<dim3(D / 32, D / 32), tb, 0, stream>>>(wq, wq_t, D, D);
    transpose_cvt_kernel<<<dim3(D / 32, D / 32), tb, 0, stream>>>(wk, wk_t, D, D);
    transpose_cvt_kernel<<<dim3(D / 32, D / 32), tb, 0, stream>>>(wv, wv_t, D, D);
    transpose_cvt_kernel<<<dim3(D / 32, D / 32), tb, 0, stream>>>(wo, wo_t, D, D);
    transpose_cvt_kernel<<<dim3(I / 32, D / 32), tb, 0, stream>>>(w1, w1_t, D, I);
    transpose_cvt_kernel<<<dim3(I / 32, D / 32), tb, 0, stream>>>(w3, w3_t, D, I);
    transpose_cvt_kernel<<<dim3(D / 32, I / 32), tb, 0, stream>>>(w2, w2_t, I, D);

    ln_kernel<<<BS, tb, 0, stream>>>(hs, ln1g, ln1b, x_b, D);

    // fused QKV GEMM (RoPE fused for q,k cols)
    gemm2_kernel<3><<<dim3(BS / G2_BM, 3072 / G2_BN), tb, 0, stream>>>(
        x_b, wq_t, nullptr, qkvb, BS, 3072, D, D, D);

    transpose_v_kernel<<<dim3(S / 64, 16, B), tb, 0, stream>>>(qkvb + 2048, vt, S, QKVS);

    attn_kernel<<<dim3(S / 64, 16, B), tb, 0, stream>>>(qkvb, vt, ctxb, S);

    gemm_kernel<1><<<dim3(D / BN, BS / BM), tb, 0, stream>>>(ctxb, wo_t, hid, hs, nullptr,
                                                             nullptr, BS, D, D);

    ln_kernel<<<BS, tb, 0, stream>>>(hid, ln2g, ln2b, x2_b, D);

    gemm2_kernel<4><<<dim3(BS / G2_BM, I / G2_BN), tb, 0, stream>>>(
        x2_b, w1_t, nullptr, h1b, BS, I, D, D, D);
    gemm2_kernel<2><<<dim3(BS / G2_BM, I / G2_BN), tb, 0, stream>>>(
        x2_b, w3_t, h1b, hbuf, BS, I, D, D, D);

    // W2: split-K x4 (K=4096 -> 4x1024), bf16 partials, then reduce + residual
    gemm2_kernel<5><<<dim3(BS / G2_BM, D / G2_BN, 4), tb, 0, stream>>>(
        hbuf, w2_t, nullptr, pker, BS, D, 1024, I, I);
    reduce4_kernel<<<dim3(BS * D / 4 / 256), tb, 0, stream>>>(pker, hid, out, BS * D / 4);
}